// Round 2
// baseline (696.920 us; speedup 1.0000x reference)
//
#include <hip/hip_runtime.h>

// CapsuleBlock dynamic routing, MI355X — R2: no hats materialization.
// x: [64, 2048, 8] f32; W: [2048, 16, 8, 16] f32; out: [64, 16, 16] f32.
// Per pass: recompute hat[b,n,k,:] from x,W. Wave owns one n, holds W frag
// in 32 VGPRs, loops 8 b's. bias2 = hat.(out0+out1); squash folded into
// route kernels. s accumulated via LDS cross-wave reduce + global atomics.

#define B_    64
#define NIN   2048
#define DIN   8
#define NOUT  16
#define DOUT  16
#define BG    8      // b's per block
#define NW    4      // waves per block = n's per block

// MODE 0: s0 += sum_n hat            (iter-0, uniform c folded into squash scale)
// MODE 1: ov = squash(s0/16);            s1 += softmax_k(hat.ov)*hat
// MODE 2: ov = squash(s0/16)+squash(s1); s2 += softmax_k(hat.ov)*hat
template<int MODE>
__global__ __launch_bounds__(256) void k_pass(const float* __restrict__ x,
                                              const float* __restrict__ W,
                                              const float* __restrict__ s0,
                                              const float* __restrict__ s1,
                                              float* __restrict__ sdst) {
    __shared__ float4 red[BG * NW * 64];   // 32 KB: [b][wave][lane]
    __shared__ float4 ovs[BG * 64];        // 8 KB:  [b][lane]

    const int tid  = threadIdx.x;
    const int lane = tid & 63;
    const int w    = tid >> 6;
    const int k    = lane >> 2;
    const int o4   = lane & 3;
    const int n    = blockIdx.x * NW + w;
    const int b0   = blockIdx.y * BG;

    // W fragment for (n,k,o4): 8 x float4, reused across all BG b's.
    const float* wp = W + ((size_t)n * NOUT + k) * (DIN * DOUT) + o4 * 4;
    float4 wf[8];
#pragma unroll
    for (int d = 0; d < 8; ++d) wf[d] = *(const float4*)(wp + d * DOUT);

    if (MODE >= 1) {
        // Each wave computes squashed output vectors for 2 b's into LDS.
#pragma unroll
        for (int r = 0; r < 2; ++r) {
            int bl = w * 2 + r;
            int b  = b0 + bl;
            float4 v = *(const float4*)&s0[b * 256 + lane * 4];
            v.x *= 0.0625f; v.y *= 0.0625f; v.z *= 0.0625f; v.w *= 0.0625f;
            float sq = v.x*v.x + v.y*v.y + v.z*v.z + v.w*v.w;
            sq += __shfl_xor(sq, 1);
            sq += __shfl_xor(sq, 2);                     // sum over this k-row's 16 o's
            float sc = sq / (1.f + sq) * rsqrtf(sq);
            float4 ov = make_float4(v.x*sc, v.y*sc, v.z*sc, v.w*sc);
            if (MODE == 2) {
                float4 u = *(const float4*)&s1[b * 256 + lane * 4];
                float q2 = u.x*u.x + u.y*u.y + u.z*u.z + u.w*u.w;
                q2 += __shfl_xor(q2, 1);
                q2 += __shfl_xor(q2, 2);
                float sc2 = q2 / (1.f + q2) * rsqrtf(q2);
                ov.x = fmaf(u.x, sc2, ov.x);
                ov.y = fmaf(u.y, sc2, ov.y);
                ov.z = fmaf(u.z, sc2, ov.z);
                ov.w = fmaf(u.w, sc2, ov.w);
            }
            ovs[bl * 64 + lane] = ov;
        }
        __syncthreads();
    }

    // Main loop: one b at a time, W frag reused from registers.
#pragma unroll
    for (int i = 0; i < BG; ++i) {
        int b = b0 + i;
        const float* xp = x + ((size_t)b * NIN + n) * DIN;
        float4 xa = *(const float4*)xp;          // wave-uniform broadcast
        float4 xb = *(const float4*)(xp + 4);
        float xs[8] = {xa.x, xa.y, xa.z, xa.w, xb.x, xb.y, xb.z, xb.w};
        float4 h = make_float4(0.f, 0.f, 0.f, 0.f);
#pragma unroll
        for (int d = 0; d < 8; ++d) {
            h.x = fmaf(xs[d], wf[d].x, h.x);
            h.y = fmaf(xs[d], wf[d].y, h.y);
            h.z = fmaf(xs[d], wf[d].z, h.z);
            h.w = fmaf(xs[d], wf[d].w, h.w);
        }
        if (MODE >= 1) {
            float4 ov = ovs[i * 64 + lane];
            float part = h.x*ov.x + h.y*ov.y + h.z*ov.z + h.w*ov.w;
            part += __shfl_xor(part, 1);
            part += __shfl_xor(part, 2);     // bias_k, uniform in 4-lane group
            float m = part;
            m = fmaxf(m, __shfl_xor(m, 4));
            m = fmaxf(m, __shfl_xor(m, 8));
            m = fmaxf(m, __shfl_xor(m, 16));
            m = fmaxf(m, __shfl_xor(m, 32)); // max over 16 k's
            float e = __expf(part - m);
            float es = e;
            es += __shfl_xor(es, 4);
            es += __shfl_xor(es, 8);
            es += __shfl_xor(es, 16);
            es += __shfl_xor(es, 32);
            float c = e / es;
            h.x *= c; h.y *= c; h.z *= c; h.w *= c;
        }
        red[(i * NW + w) * 64 + lane] = h;
    }
    __syncthreads();

    // Cross-wave reduce (sum 4 n's) + global atomic accumulate.
#pragma unroll
    for (int r = 0; r < 2; ++r) {
        int idx = r * 256 + tid;             // idx = bl*64 + ln
        int bl = idx >> 6, ln = idx & 63;
        float4 a  = red[(bl * NW + 0) * 64 + ln];
        float4 c1 = red[(bl * NW + 1) * 64 + ln];
        float4 c2 = red[(bl * NW + 2) * 64 + ln];
        float4 c3 = red[(bl * NW + 3) * 64 + ln];
        a.x += c1.x + c2.x + c3.x;
        a.y += c1.y + c2.y + c3.y;
        a.z += c1.z + c2.z + c3.z;
        a.w += c1.w + c2.w + c3.w;
        float* sp = sdst + (b0 + bl) * 256 + ln * 4;
        atomicAdd(sp + 0, a.x);
        atomicAdd(sp + 1, a.y);
        atomicAdd(sp + 2, a.z);
        atomicAdd(sp + 3, a.w);
    }
}

// Final squash over o: t = k*16 + o.
__global__ __launch_bounds__(256) void k_squash(const float* __restrict__ s,
                                                float scale,
                                                float* __restrict__ out) {
    int b = blockIdx.x;
    int t = threadIdx.x;
    float v = s[b * 256 + t] * scale;
    float sq = v * v;
    sq += __shfl_xor(sq, 1);
    sq += __shfl_xor(sq, 2);
    sq += __shfl_xor(sq, 4);
    sq += __shfl_xor(sq, 8);   // sum over 16-lane (same-k) group
    float sc = (sq / (1.f + sq)) * rsqrtf(sq);
    out[b * 256 + t] = v * sc;
}

extern "C" void kernel_launch(void* const* d_in, const int* in_sizes, int n_in,
                              void* d_out, int out_size, void* d_ws, size_t ws_size,
                              hipStream_t stream) {
    const float* x = (const float*)d_in[0];
    const float* W = (const float*)d_in[1];
    float* out = (float*)d_out;

    float* s0 = (float*)d_ws;                  // [64][256]
    float* s1 = s0 + B_ * 256;
    float* s2 = s1 + B_ * 256;

    hipMemsetAsync(s0, 0, (size_t)3 * B_ * 256 * sizeof(float), stream);

    dim3 grid(NIN / NW, B_ / BG);              // (512, 8); x fastest => per-XCD
                                               // W footprint 2 MB (L2-resident)
    k_pass<0><<<grid, 256, 0, stream>>>(x, W, nullptr, nullptr, s0);
    k_pass<1><<<grid, 256, 0, stream>>>(x, W, s0, nullptr, s1);
    k_pass<2><<<grid, 256, 0, stream>>>(x, W, s0, s1, s2);
    k_squash<<<B_, 256, 0, stream>>>(s2, 1.f, out);
}

// Round 3
// 176.520 us; speedup vs baseline: 3.9481x; 3.9481x over previous
//
#include <hip/hip_runtime.h>

// CapsuleBlock dynamic routing, MI355X — R3: R2 compute + atomic-free reduce.
// x: [64, 2048, 8] f32; W: [2048, 16, 8, 16] f32; out: [64, 16, 16] f32.
// Wave owns n (W frag in 32 VGPRs, reused over 8 b), loops 8 n-steps.
// Block partial -> private ws slice; k_reduce sums 64 partials per b.
// R2 lesson: device-scope atomics (8.4M onto 64KB) = 128MB HBM RMW, 228us/pass.

#define B_    64
#define NIN   2048
#define DIN   8
#define NOUT  16
#define DOUT  16
#define BG    8      // b's per block
#define NW    4      // waves per block
#define NSTEP 8      // n's per wave
#define NCHUNK (NW * NSTEP)          // 32 n per block
#define NBLK_N (NIN / NCHUNK)        // 64
#define PSTRIDE (BG * NOUT * DOUT)   // 2048 floats per block partial

// MODE 0: s0 = sum_n hat            (iter-0 softmax uniform; 1/16 in squash)
// MODE 1: ov = squash(s0/16);            s1 = sum_n softmax_k(hat.ov)*hat
// MODE 2: ov = squash(s0/16)+squash(s1); s2 = sum_n softmax_k(hat.ov)*hat
template<int MODE>
__global__ __launch_bounds__(256) void k_pass(const float* __restrict__ x,
                                              const float* __restrict__ W,
                                              const float* __restrict__ s0,
                                              const float* __restrict__ s1,
                                              float* __restrict__ partial) {
    __shared__ float4 red[BG * NW * 64];   // 32 KB
    __shared__ float4 ovs[BG * 64];        // 8 KB

    const int tid  = threadIdx.x;
    const int lane = tid & 63;
    const int w    = tid >> 6;
    const int k    = lane >> 2;
    const int o4   = lane & 3;
    const int nbase = blockIdx.x * NCHUNK + w * NSTEP;
    const int b0    = blockIdx.y * BG;

    if (MODE >= 1) {
#pragma unroll
        for (int r = 0; r < 2; ++r) {
            int bl = w * 2 + r;
            int b  = b0 + bl;
            float4 v = *(const float4*)&s0[b * 256 + lane * 4];
            v.x *= 0.0625f; v.y *= 0.0625f; v.z *= 0.0625f; v.w *= 0.0625f;
            float sq = v.x*v.x + v.y*v.y + v.z*v.z + v.w*v.w;
            sq += __shfl_xor(sq, 1);
            sq += __shfl_xor(sq, 2);                 // sum over k-row's 16 o's
            float sc = sq / (1.f + sq) * rsqrtf(sq);
            float4 ov = make_float4(v.x*sc, v.y*sc, v.z*sc, v.w*sc);
            if (MODE == 2) {
                float4 u = *(const float4*)&s1[b * 256 + lane * 4];
                float q2 = u.x*u.x + u.y*u.y + u.z*u.z + u.w*u.w;
                q2 += __shfl_xor(q2, 1);
                q2 += __shfl_xor(q2, 2);
                float sc2 = q2 / (1.f + q2) * rsqrtf(q2);
                ov.x = fmaf(u.x, sc2, ov.x);
                ov.y = fmaf(u.y, sc2, ov.y);
                ov.z = fmaf(u.z, sc2, ov.z);
                ov.w = fmaf(u.w, sc2, ov.w);
            }
            ovs[bl * 64 + lane] = ov;
        }
        __syncthreads();
    }

    float4 acc[BG];
#pragma unroll
    for (int i = 0; i < BG; ++i) acc[i] = make_float4(0.f, 0.f, 0.f, 0.f);

    for (int it = 0; it < NSTEP; ++it) {
        int n = nbase + it;
        const float* wp = W + ((size_t)n * NOUT + k) * (DIN * DOUT) + o4 * 4;
        float4 wf[8];
#pragma unroll
        for (int d = 0; d < 8; ++d) wf[d] = *(const float4*)(wp + d * DOUT);

#pragma unroll
        for (int i = 0; i < BG; ++i) {
            int b = b0 + i;
            const float* xp = x + ((size_t)b * NIN + n) * DIN;
            float4 xa = *(const float4*)xp;      // wave-uniform broadcast
            float4 xb = *(const float4*)(xp + 4);
            float xs[8] = {xa.x, xa.y, xa.z, xa.w, xb.x, xb.y, xb.z, xb.w};
            float4 h = make_float4(0.f, 0.f, 0.f, 0.f);
#pragma unroll
            for (int d = 0; d < 8; ++d) {
                h.x = fmaf(xs[d], wf[d].x, h.x);
                h.y = fmaf(xs[d], wf[d].y, h.y);
                h.z = fmaf(xs[d], wf[d].z, h.z);
                h.w = fmaf(xs[d], wf[d].w, h.w);
            }
            if (MODE >= 1) {
                float4 ov = ovs[i * 64 + lane];
                float part = h.x*ov.x + h.y*ov.y + h.z*ov.z + h.w*ov.w;
                part += __shfl_xor(part, 1);
                part += __shfl_xor(part, 2);     // bias_k, uniform per 4-lane group
                float m = part;
                m = fmaxf(m, __shfl_xor(m, 4));
                m = fmaxf(m, __shfl_xor(m, 8));
                m = fmaxf(m, __shfl_xor(m, 16));
                m = fmaxf(m, __shfl_xor(m, 32));
                float e = __expf(part - m);
                float es = e;
                es += __shfl_xor(es, 4);
                es += __shfl_xor(es, 8);
                es += __shfl_xor(es, 16);
                es += __shfl_xor(es, 32);
                float c = e / es;
                h.x *= c; h.y *= c; h.z *= c; h.w *= c;
            }
            acc[i].x += h.x; acc[i].y += h.y; acc[i].z += h.z; acc[i].w += h.w;
        }
    }

#pragma unroll
    for (int i = 0; i < BG; ++i) red[(i * NW + w) * 64 + lane] = acc[i];
    __syncthreads();

    // Cross-wave reduce + write block partial (no atomics).
    float* pbase = partial + ((size_t)blockIdx.y * NBLK_N + blockIdx.x) * PSTRIDE;
#pragma unroll
    for (int r = 0; r < 2; ++r) {
        int idx = r * 256 + tid;             // idx = bl*64 + ln
        int bl = idx >> 6, ln = idx & 63;
        float4 a  = red[(bl * NW + 0) * 64 + ln];
        float4 c1 = red[(bl * NW + 1) * 64 + ln];
        float4 c2 = red[(bl * NW + 2) * 64 + ln];
        float4 c3 = red[(bl * NW + 3) * 64 + ln];
        a.x += c1.x + c2.x + c3.x;
        a.y += c1.y + c2.y + c3.y;
        a.z += c1.z + c2.z + c3.z;
        a.w += c1.w + c2.w + c3.w;
        *(float4*)&pbase[bl * 256 + ln * 4] = a;
    }
}

// Sum 64 block-partials per b: s[b][t] = sum_nc partial[(bg*64+nc)][bl*256+t].
__global__ __launch_bounds__(256) void k_reduce(const float* __restrict__ partial,
                                                float* __restrict__ s) {
    int b = blockIdx.x;
    int bg = b >> 3, bl = b & 7;
    int t = threadIdx.x;
    const float* p = partial + (size_t)bg * NBLK_N * PSTRIDE + bl * 256 + t;
    float a = 0.f;
#pragma unroll 8
    for (int nc = 0; nc < NBLK_N; ++nc) a += p[(size_t)nc * PSTRIDE];
    s[b * 256 + t] = a;
}

// Final squash over o: t = k*16 + o.
__global__ __launch_bounds__(256) void k_squash(const float* __restrict__ s,
                                                float scale,
                                                float* __restrict__ out) {
    int b = blockIdx.x;
    int t = threadIdx.x;
    float v = s[b * 256 + t] * scale;
    float sq = v * v;
    sq += __shfl_xor(sq, 1);
    sq += __shfl_xor(sq, 2);
    sq += __shfl_xor(sq, 4);
    sq += __shfl_xor(sq, 8);   // sum over 16-lane (same-k) group
    float sc = (sq / (1.f + sq)) * rsqrtf(sq);
    out[b * 256 + t] = v * sc;
}

extern "C" void kernel_launch(void* const* d_in, const int* in_sizes, int n_in,
                              void* d_out, int out_size, void* d_ws, size_t ws_size,
                              hipStream_t stream) {
    const float* x = (const float*)d_in[0];
    const float* W = (const float*)d_in[1];
    float* out = (float*)d_out;

    float* s0 = (float*)d_ws;                       // [64][256]
    float* s1 = s0 + B_ * 256;
    float* s2 = s1 + B_ * 256;
    float* partial = s2 + B_ * 256;                 // [512][2048] = 4 MB, reused

    dim3 grid(NBLK_N, B_ / BG);                     // (64, 8) = 512 blocks

    k_pass<0><<<grid, 256, 0, stream>>>(x, W, nullptr, nullptr, partial);
    k_reduce<<<B_, 256, 0, stream>>>(partial, s0);
    k_pass<1><<<grid, 256, 0, stream>>>(x, W, s0, nullptr, partial);
    k_reduce<<<B_, 256, 0, stream>>>(partial, s1);
    k_pass<2><<<grid, 256, 0, stream>>>(x, W, s0, s1, partial);
    k_reduce<<<B_, 256, 0, stream>>>(partial, s2);
    k_squash<<<B_, 256, 0, stream>>>(s2, 1.f, out);
}

// Round 4
// 156.632 us; speedup vs baseline: 4.4494x; 1.1270x over previous
//
#include <hip/hip_runtime.h>

// CapsuleBlock dynamic routing, MI355X — R4: occupancy + leaner routing math.
// x: [64, 2048, 8] f32; W: [2048, 16, 8, 16] f32; out: [64, 16, 16] f32.
// R3 lesson: 512 blocks = 2 waves/SIMD -> VALUBusy 25%, latency-starved.
// R4: grid (256,4)=1024 blocks, 16 waves/CU; waves own disjoint b (no LDS
// reduce); x tile in LDS; no softmax max-sub (bias bounded ~20 << 88).

#define B_    64
#define NIN   2048
#define DIN   8
#define NOUT  16
#define DOUT  16
#define NW    4                // waves per block
#define BGW   4                // b per wave
#define BGB   (NW * BGW)       // 16 b per block
#define NC    8                // n per block (shared by all waves)
#define GX    (NIN / NC)       // 256
#define GY    (B_ / BGB)       // 4

// MODE 0: s0 = sum_n hat                       (uniform c; 1/16 applied later)
// MODE 1: ov = squash(s0/16);                  s1 = sum_n softmax_k(hat.ov)*hat
// MODE 2: ov = squash(s0/16)+squash(s1);       s2 = sum_n softmax_k(hat.ov)*hat
template<int MODE>
__global__ __launch_bounds__(256, 4) void k_pass(const float* __restrict__ x,
                                                 const float* __restrict__ W,
                                                 const float* __restrict__ s0,
                                                 const float* __restrict__ s1,
                                                 float* __restrict__ partial) {
    __shared__ float4 xt[BGB][NC][2];   // 4 KB  x[b0+bl][nbase+nn][j*4..]
    __shared__ float4 ovs[BGB * 64];    // 16 KB (only used MODE>=1)

    const int tid  = threadIdx.x;
    const int lane = tid & 63;
    const int w    = tid >> 6;
    const int k    = lane >> 2;
    const int o4   = lane & 3;
    const int nbase = blockIdx.x * NC;
    const int b0    = blockIdx.y * BGB;

    // Stage x tile: 256 float4s, one per thread. 16-lane runs are contiguous.
    {
        int bl = tid >> 4, rest = tid & 15, nn = rest >> 1, j = rest & 1;
        xt[bl][nn][j] =
            *(const float4*)(x + ((size_t)(b0 + bl) * NIN + nbase + nn) * DIN + j * 4);
    }

    if (MODE >= 1) {
        // Each wave computes squashed output vectors for its 4 b's.
#pragma unroll
        for (int r = 0; r < BGW; ++r) {
            int bl = w * BGW + r;
            int b  = b0 + bl;
            float4 v = *(const float4*)&s0[b * 256 + lane * 4];
            v.x *= 0.0625f; v.y *= 0.0625f; v.z *= 0.0625f; v.w *= 0.0625f;
            float sq = v.x*v.x + v.y*v.y + v.z*v.z + v.w*v.w;
            sq += __shfl_xor(sq, 1);
            sq += __shfl_xor(sq, 2);                 // sum over k-row's 16 o's
            float sc = sq / (1.f + sq) * rsqrtf(sq);
            float4 ov = make_float4(v.x*sc, v.y*sc, v.z*sc, v.w*sc);
            if (MODE == 2) {
                float4 u = *(const float4*)&s1[b * 256 + lane * 4];
                float q2 = u.x*u.x + u.y*u.y + u.z*u.z + u.w*u.w;
                q2 += __shfl_xor(q2, 1);
                q2 += __shfl_xor(q2, 2);
                float sc2 = q2 / (1.f + q2) * rsqrtf(q2);
                ov.x = fmaf(u.x, sc2, ov.x);
                ov.y = fmaf(u.y, sc2, ov.y);
                ov.z = fmaf(u.z, sc2, ov.z);
                ov.w = fmaf(u.w, sc2, ov.w);
            }
            ovs[bl * 64 + lane] = ov;
        }
    }
    __syncthreads();

    float4 acc[BGW];
#pragma unroll
    for (int i = 0; i < BGW; ++i) acc[i] = make_float4(0.f, 0.f, 0.f, 0.f);

    for (int nn = 0; nn < NC; ++nn) {
        const float* wp = W + ((size_t)(nbase + nn) * NOUT + k) * (DIN * DOUT) + o4 * 4;
        float4 wf[8];
#pragma unroll
        for (int d = 0; d < 8; ++d) wf[d] = *(const float4*)(wp + d * DOUT);

#pragma unroll
        for (int i = 0; i < BGW; ++i) {
            int bl = w * BGW + i;
            float4 xa = xt[bl][nn][0];           // wave-uniform -> LDS broadcast
            float4 xb = xt[bl][nn][1];
            float xs[8] = {xa.x, xa.y, xa.z, xa.w, xb.x, xb.y, xb.z, xb.w};
            float4 h = make_float4(0.f, 0.f, 0.f, 0.f);
#pragma unroll
            for (int d = 0; d < 8; ++d) {
                h.x = fmaf(xs[d], wf[d].x, h.x);
                h.y = fmaf(xs[d], wf[d].y, h.y);
                h.z = fmaf(xs[d], wf[d].z, h.z);
                h.w = fmaf(xs[d], wf[d].w, h.w);
            }
            if (MODE >= 1) {
                float4 ov = ovs[bl * 64 + lane];
                float part = h.x * ov.x;
                part = fmaf(h.y, ov.y, part);
                part = fmaf(h.z, ov.z, part);
                part = fmaf(h.w, ov.w, part);
                part += __shfl_xor(part, 1);
                part += __shfl_xor(part, 2);     // bias_k (uniform per 4-lane grp)
                // |bias| <~ 20 << 88: raw exp is safe in f32, skip max-sub.
                float e = __expf(part);
                float es = e;
                es += __shfl_xor(es, 4);
                es += __shfl_xor(es, 8);
                es += __shfl_xor(es, 16);
                es += __shfl_xor(es, 32);        // sum over 16 k's
                float c = __fdividef(e, es);
                h.x *= c; h.y *= c; h.z *= c; h.w *= c;
            }
            acc[i].x += h.x; acc[i].y += h.y; acc[i].z += h.z; acc[i].w += h.w;
        }
    }

    // Waves own disjoint b -> direct wave-private partial store, no reduce.
    float* pbase = partial + ((size_t)blockIdx.y * GX + blockIdx.x) * (BGB * 256);
#pragma unroll
    for (int i = 0; i < BGW; ++i)
        *(float4*)&pbase[(w * BGW + i) * 256 + lane * 4] = acc[i];
}

// s[b][t] = sum_x partial[(y*GX+x)*BGB*256 + bl*256 + t],  b = y*16+bl.
__global__ __launch_bounds__(64) void k_reduce(const float* __restrict__ partial,
                                               float* __restrict__ s) {
    int b = blockIdx.x, q = blockIdx.y;
    int t = q * 64 + threadIdx.x;
    int y = b >> 4, bl = b & 15;
    const float* base = partial + ((size_t)y * GX * BGB + bl) * 256 + t;
    float a = 0.f;
#pragma unroll 8
    for (int xx = 0; xx < GX; ++xx)
        a += base[(size_t)xx * BGB * 256];
    s[b * 256 + t] = a;
}

// Final squash over o: t = k*16 + o.
__global__ __launch_bounds__(256) void k_squash(const float* __restrict__ s,
                                                float scale,
                                                float* __restrict__ out) {
    int b = blockIdx.x;
    int t = threadIdx.x;
    float v = s[b * 256 + t] * scale;
    float sq = v * v;
    sq += __shfl_xor(sq, 1);
    sq += __shfl_xor(sq, 2);
    sq += __shfl_xor(sq, 4);
    sq += __shfl_xor(sq, 8);   // sum over 16-lane (same-k) group
    float sc = (sq / (1.f + sq)) * rsqrtf(sq);
    out[b * 256 + t] = v * sc;
}

extern "C" void kernel_launch(void* const* d_in, const int* in_sizes, int n_in,
                              void* d_out, int out_size, void* d_ws, size_t ws_size,
                              hipStream_t stream) {
    const float* x = (const float*)d_in[0];
    const float* W = (const float*)d_in[1];
    float* out = (float*)d_out;

    float* s0 = (float*)d_ws;                 // [64][256] each (64 KB)
    float* s1 = s0 + B_ * 256;
    float* s2 = s1 + B_ * 256;
    float* partial = s2 + B_ * 256;           // GY*GX*BGB*256 f32 = 16 MB

    dim3 grid(GX, GY);                        // (256, 4) = 1024 blocks
    dim3 rgrid(B_, 4);

    k_pass<0><<<grid, 256, 0, stream>>>(x, W, nullptr, nullptr, partial);
    k_reduce<<<rgrid, 64, 0, stream>>>(partial, s0);
    k_pass<1><<<grid, 256, 0, stream>>>(x, W, s0, nullptr, partial);
    k_reduce<<<rgrid, 64, 0, stream>>>(partial, s1);
    k_pass<2><<<grid, 256, 0, stream>>>(x, W, s0, s1, partial);
    k_reduce<<<rgrid, 64, 0, stream>>>(partial, s2);
    k_squash<<<B_, 256, 0, stream>>>(s2, 1.f, out);
}